// Round 1
// 562.006 us; speedup vs baseline: 1.0990x; 1.0990x over previous
//
#include <hip/hip_runtime.h>
#include <hip/hip_bf16.h>

typedef __bf16 bf16;
typedef __bf16 bf16x4 __attribute__((ext_vector_type(4)));
typedef __bf16 bf16x8 __attribute__((ext_vector_type(8)));
typedef float  f32x4  __attribute__((ext_vector_type(4)));

#define AS1 __attribute__((address_space(1)))
#define AS3 __attribute__((address_space(3)))

__device__ __forceinline__ void gld_lds16(const void* g, void* l) {
    // async global->LDS, 16B per lane; LDS dest = wave-uniform base + lane*16
    __builtin_amdgcn_global_load_lds((AS1 void*)g, (AS3 void*)l, 16, 0, 0);
}

// ---------------------------------------------------------------------------
// fp32 -> bf16 bulk convert, float4-vectorized grid-stride
// ---------------------------------------------------------------------------
__global__ void cvt_kernel(const float* __restrict__ in, bf16* __restrict__ out,
                           int n4) {
    for (long i = (long)blockIdx.x * blockDim.x + threadIdx.x; i < n4;
         i += (long)gridDim.x * blockDim.x) {
        f32x4 v = ((const f32x4*)in)[i];
        bf16x4 h;
#pragma unroll
        for (int e = 0; e < 4; ++e) h[e] = (bf16)v[e];
        ((bf16x4*)out)[i] = h;
    }
}

// ---------------------------------------------------------------------------
// bias[h][i][j] = table[rel_index[i*64+j]][h]   (all fp32)
// ---------------------------------------------------------------------------
__global__ void bias_kernel(const int* __restrict__ rel_index,
                            const float* __restrict__ table,
                            float* __restrict__ bias) {
    int idx = blockIdx.x * 256 + threadIdx.x;   // 0..65535 = h*4096 + rc
    int rc = idx & 4095;
    int h  = idx >> 12;
    bias[idx] = table[rel_index[rc] * 16 + h];
}

// ---------------------------------------------------------------------------
// GEMM1 (qkv): C[m,n] = sum_k A[m,k]*B[n,k] + bias[n], A,B bf16.
// 256x256 tile, BK=64, 512 thr (8 waves, 2Mx4N), 8-phase counted-vmcnt
// schedule (T3+T4) + setprio (T5) + XCD-chunked swizzle (T1).
// LDS: sA/sB [2 slot][2 kk][256 rows][32 k] -> 64-B rows = bank-uniform
// fragment reads (no swizzle needed).  M=65536, N=1536, K=512 (8 K-tiles,
// 4 main iterations of 2 tiles each).
// Epilogue: acc -> swizzled LDS C-tile (bf16) -> vectorized 16B stores.
// ---------------------------------------------------------------------------
#define STAGE(GBASE, LBASE, SK0)                                          \
    { _Pragma("unroll")                                                   \
      for (int c_ = 0; c_ < 2; ++c_)                                      \
          gld_lds16((GBASE) + c_ * 16 * 512 + (SK0),                      \
                    (LBASE) + (w * 2 + c_) * 512); }

// One phase: ds-read fragments | issue one K-half stage | barrier |
// lgkmcnt(0) | 16 MFMA (setprio) | [vmcnt(4)] | barrier.
#define PHASE(S, KK, IH, LOADB, GB, LB, SK0, VM)                            \
  {                                                                         \
    const bf16* ap_ = sA + ((S)*2+(KK))*8192 + (wm128+(IH)*64+r16)*32 + q*8;\
    _Pragma("unroll")                                                       \
    for (int ii = 0; ii < 4; ++ii) av[ii] = *(const bf16x8*)(ap_ + ii*512); \
    if (LOADB) {                                                            \
      const bf16* bp_ = sB + ((S)*2+(KK))*8192 + (wn64+r16)*32 + q*8;       \
      _Pragma("unroll")                                                     \
      for (int jj = 0; jj < 4; ++jj) bv[jj] = *(const bf16x8*)(bp_+jj*512); \
    }                                                                       \
    STAGE(GB, LB, SK0);                                                     \
    __builtin_amdgcn_sched_barrier(0);                                      \
    __builtin_amdgcn_s_barrier();                                           \
    asm volatile("s_waitcnt lgkmcnt(0)");                                   \
    __builtin_amdgcn_sched_barrier(0);                                      \
    __builtin_amdgcn_s_setprio(1);                                          \
    _Pragma("unroll")                                                       \
    for (int ii = 0; ii < 4; ++ii)                                          \
      _Pragma("unroll")                                                     \
      for (int jj = 0; jj < 4; ++jj)                                        \
        acc[(IH)*4+ii][jj] = __builtin_amdgcn_mfma_f32_16x16x32_bf16(       \
            av[ii], bv[jj], acc[(IH)*4+ii][jj], 0, 0, 0);                   \
    __builtin_amdgcn_s_setprio(0);                                          \
    if (VM) asm volatile("s_waitcnt vmcnt(4)");                             \
    __builtin_amdgcn_sched_barrier(0);                                      \
    __builtin_amdgcn_s_barrier();                                           \
  }

__global__ __launch_bounds__(512, 2) void gemm1_qkv8(
    const bf16* __restrict__ A, const bf16* __restrict__ B,
    const float* __restrict__ bias, bf16* __restrict__ Cq,
    bf16* __restrict__ Ckv)
{
    __shared__ __attribute__((aligned(16))) char smemraw[131072];  // 128 KB
    bf16* sA = (bf16*)smemraw;       // [2 slot][2 kk][256*32]
    bf16* sB = sA + 32768;

    const int t     = threadIdx.x;
    const int w     = t >> 6;
    const int lane  = t & 63;
    const int q     = lane >> 4;
    const int r16   = lane & 15;
    const int wm128 = (w >> 2) * 128;
    const int wn64  = (w & 3) * 64;

    // XCD-chunked bijective swizzle (nwg=1536=8*192), N-fastest in chunk:
    // each 256-row A panel is consumed by exactly one XCD (6 consecutive wgs).
    const int bid = blockIdx.x;
    const int wg  = (bid & 7) * 192 + (bid >> 3);
    const long bM = (long)(wg / 6) * 256;
    const long bN = (long)(wg % 6) * 256;

    // per-thread staging source bases: row = base + w*32 + c*16 + lane/4,
    // col = (lane&3)*8 within the selected 32-wide K-half
    const bf16* Ast = A + (bM + w * 32 + (lane >> 2)) * 512 + (lane & 3) * 8;
    const bf16* Bst = B + (bN + w * 32 + (lane >> 2)) * 512 + (lane & 3) * 8;

    f32x4 acc[8][4];
#pragma unroll
    for (int i = 0; i < 8; ++i)
#pragma unroll
        for (int j = 0; j < 4; ++j) acc[i][j] = f32x4{0.f, 0.f, 0.f, 0.f};

    bf16x8 av[4], bv[4];

    // prologue: tile0 fully (slot0 kk0+kk1), tile1 K0 (slot1 kk0). 12 loads,
    // retire the first 8 (tile0) with vmcnt(4).
    STAGE(Ast, sA + 0,     0);
    STAGE(Bst, sB + 0,     0);
    STAGE(Ast, sA + 8192,  32);
    STAGE(Bst, sB + 8192,  32);
    STAGE(Ast, sA + 16384, 64);
    STAGE(Bst, sB + 16384, 64);
    asm volatile("s_waitcnt vmcnt(4)");
    __builtin_amdgcn_sched_barrier(0);
    __builtin_amdgcn_s_barrier();

    // main loop: iter i computes tiles 2i (slot0, ph1-4) and 2i+1 (slot1,
    // ph5-8).  Staging stagger (2 loads/phase, all regions disjoint from
    // the phase's reads and from in-flight writes):
    //  ph1: s1.K1A<-t1  ph2: s1.K1B<-t1  ph3: s0.K0A<-t2  ph4: s0.K0B<-t2
    //  ph5: s0.K1A<-t2  ph6: s0.K1B<-t2  ph7: s1.K0A<-t3  ph8: s1.K0B<-t3
    // vmcnt(4) at ph4 (slot1 fully landed) and ph8 (slot0/t2 fully landed).
    for (int i = 0; i < 4; ++i) {
        const int t1 = 2 * i + 1;
        const int t2 = (2 * i + 2 < 8) ? 2 * i + 2 : 7;  // clamp keeps vmcnt
        const int t3 = (2 * i + 3 < 8) ? 2 * i + 3 : 7;  // counting uniform
        PHASE(0, 0, 0, 1, Ast, sA + 24576, t1 * 64 + 32, 0)
        PHASE(0, 0, 1, 0, Bst, sB + 24576, t1 * 64 + 32, 0)
        PHASE(0, 1, 1, 1, Ast, sA + 0,     t2 * 64,      0)
        PHASE(0, 1, 0, 0, Bst, sB + 0,     t2 * 64,      1)
        PHASE(1, 0, 0, 1, Ast, sA + 8192,  t2 * 64 + 32, 0)
        PHASE(1, 0, 1, 0, Bst, sB + 8192,  t2 * 64 + 32, 0)
        PHASE(1, 1, 1, 1, Ast, sA + 16384, t3 * 64,      0)
        PHASE(1, 1, 0, 0, Bst, sB + 16384, t3 * 64,      1)
    }

    // drain clamped prefetches before reusing LDS for the C-tile
    asm volatile("s_waitcnt vmcnt(0)");
    __builtin_amdgcn_sched_barrier(0);
    __builtin_amdgcn_s_barrier();

    // epilogue: acc -> LDS bf16 [256][256], 16B-chunk XOR-swizzled by row
    // to break write/read conflicts, then cooperative vectorized stores.
    bf16* ct = (bf16*)smemraw;
#pragma unroll
    for (int j = 0; j < 4; ++j) {
        const int col  = wn64 + j * 16 + r16;
        const float bvv = bias[bN + col];
        const int chunk = col >> 3, cl = col & 7;
#pragma unroll
        for (int i = 0; i < 8; ++i)
#pragma unroll
            for (int r = 0; r < 4; ++r) {
                const int row = wm128 + i * 16 + q * 4 + r;
                ct[row * 256 + ((chunk ^ ((row >> 2) & 7)) << 3) + cl] =
                    (bf16)(acc[i][j][r] + bvv);
            }
    }
    __syncthreads();

    const bool isQ = (bN < 512);                   // block-uniform
    bf16* __restrict__ outp = isQ ? (Cq + bM * 512 + bN)
                                  : (Ckv + bM * 1024 + (bN - 512));
    const int ostr = isQ ? 512 : 1024;
#pragma unroll
    for (int it = 0; it < 16; ++it) {
        const int row = w * 32 + it * 2 + (lane >> 5);  // 2 full rows / wave
        const int c   = lane & 31;
        uint4 v = *(const uint4*)(ct + row * 256 +
                                  ((c ^ ((row >> 2) & 7)) << 3));
        *(uint4*)(outp + (long)row * ostr + c * 8) = v;
    }
}

// ---------------------------------------------------------------------------
// GEMM2 (proj): C[m,n] = sum_k A[m,k]*B[n,k] + bias[n]
// A bf16 (attn out, stride 512), B bf16 (pre-converted proj_w), C fp32.
// M=65536, N=512, K=512.  (unchanged this round — isolate gemm1 experiment)
// ---------------------------------------------------------------------------
__global__ __launch_bounds__(256) void gemm2_proj(
    const bf16* __restrict__ A, const bf16* __restrict__ B,
    const float* __restrict__ bias, float* __restrict__ C)
{
    __shared__ __attribute__((aligned(16))) bf16 As[128 * 64];
    __shared__ __attribute__((aligned(16))) bf16 Bs[128 * 64];

    const int t    = threadIdx.x;
    const int w    = t >> 6;
    const int lane = t & 63;
    const int q    = lane >> 4;
    const int r16  = lane & 15;
    const int wm   = (w & 1) * 64;
    const int wn   = (w >> 1) * 64;
    const long bM  = (long)blockIdx.x * 128;
    const long bN  = (long)blockIdx.y * 128;

    const int sRow = lane >> 3;
    const int sCol = (lane & 7) * 8;

    f32x4 acc[4][4];
#pragma unroll
    for (int i = 0; i < 4; ++i)
#pragma unroll
        for (int j = 0; j < 4; ++j)
            acc[i][j] = f32x4{0.f, 0.f, 0.f, 0.f};

    for (int k0 = 0; k0 < 512; k0 += 64) {
#pragma unroll
        for (int it = 0; it < 4; ++it) {
            const int chunk = w * 4 + it;
            const int row   = chunk * 8 + sRow;
            gld_lds16(A + (bM + row) * 512L + k0 + sCol, As + chunk * 512);
            gld_lds16(B + (bN + row) * 512L + k0 + sCol, Bs + chunk * 512);
        }
        asm volatile("s_waitcnt vmcnt(0)" ::: "memory");
        __syncthreads();

#pragma unroll
        for (int ks = 0; ks < 2; ++ks) {
            bf16x8 av[4], bv[4];
#pragma unroll
            for (int i = 0; i < 4; ++i)
                av[i] = *(const bf16x8*)&As[(wm + i * 16 + r16) * 64 + ks * 32 + q * 8];
#pragma unroll
            for (int j = 0; j < 4; ++j)
                bv[j] = *(const bf16x8*)&Bs[(wn + j * 16 + r16) * 64 + ks * 32 + q * 8];
#pragma unroll
            for (int i = 0; i < 4; ++i)
#pragma unroll
                for (int j = 0; j < 4; ++j)
                    acc[i][j] = __builtin_amdgcn_mfma_f32_16x16x32_bf16(
                        av[i], bv[j], acc[i][j], 0, 0, 0);
        }
        __syncthreads();
    }

#pragma unroll
    for (int j = 0; j < 4; ++j) {
        const long col = bN + wn + j * 16 + r16;
        const float bvv = bias[col];
#pragma unroll
        for (int i = 0; i < 4; ++i) {
            const long row = bM + wm + i * 16 + q * 4;
#pragma unroll
            for (int r = 0; r < 4; ++r)
                C[(row + r) * 512L + col] = acc[i][j][r] + bvv;
        }
    }
}

// ---------------------------------------------------------------------------
// Window attention: one wave per (window bw, head h).
// qbuf: (65536,512) bf16 = q; kv: (65536,1024) bf16 = [k | v].
// Output written IN PLACE into qbuf cols h*32..h*32+31.
// ---------------------------------------------------------------------------
__global__ __launch_bounds__(64) void attn_kernel(
    bf16* __restrict__ qbuf, const bf16* __restrict__ kv,
    const float* __restrict__ mask, const float* __restrict__ bias)
{
    __shared__ __attribute__((aligned(16))) bf16 smem[6144];  // 12 KB
    bf16* Qs = smem;          // [64][32]
    bf16* Ks = smem + 2048;   // [64][32]
    bf16* Vt = smem + 4096;   // [32][64]
    bf16* Ps = smem;          // [64][64] reuses Qs+Ks

    const int lane = threadIdx.x;
    const int q    = lane >> 4;
    const int r16  = lane & 15;
    const int bw   = blockIdx.x >> 4;
    const int h    = blockIdx.x & 15;
    const int nw   = bw & 63;
    const long rowbase = (long)bw * 64;

#pragma unroll
    for (int it = 0; it < 4; ++it) {
        const int tok  = it * 16 + (lane >> 2);
        const int part = (lane & 3) * 8;
        gld_lds16(qbuf + (rowbase + tok) * 512  + h * 32 + part, Qs + it * 512);
        gld_lds16(kv   + (rowbase + tok) * 1024 + h * 32 + part, Ks + it * 512);
    }
    {
        const bf16* gv = kv + (rowbase + lane) * 1024 + 512 + h * 32;
        uint4 vtmp[4];
#pragma unroll
        for (int jj = 0; jj < 4; ++jj) vtmp[jj] = ((const uint4*)gv)[jj];
        const bf16* vrow = (const bf16*)vtmp;
#pragma unroll
        for (int hd = 0; hd < 32; ++hd)
            Vt[hd * 64 + lane] = vrow[hd];
    }
    asm volatile("s_waitcnt vmcnt(0)" ::: "memory");
    __syncthreads();

    f32x4 acc[4][4];
    {
        bf16x8 av[4], bv[4];
#pragma unroll
        for (int ti = 0; ti < 4; ++ti)
            av[ti] = *(const bf16x8*)&Qs[(ti * 16 + r16) * 32 + q * 8];
#pragma unroll
        for (int tj = 0; tj < 4; ++tj)
            bv[tj] = *(const bf16x8*)&Ks[(tj * 16 + r16) * 32 + q * 8];
        const f32x4 z = f32x4{0.f, 0.f, 0.f, 0.f};
#pragma unroll
        for (int ti = 0; ti < 4; ++ti)
#pragma unroll
            for (int tj = 0; tj < 4; ++tj)
                acc[ti][tj] = __builtin_amdgcn_mfma_f32_16x16x32_bf16(
                    av[ti], bv[tj], z, 0, 0, 0);
    }

    const float SCALE  = 0.17677669529663687f;   // 1/sqrt(32)
    const float LOG2E  = 1.4426950408889634f;
    const float* biasH = bias + h * 4096;
    const float* maskW = mask + nw * 4096;

#pragma unroll
    for (int ti = 0; ti < 4; ++ti) {
#pragma unroll
        for (int r = 0; r < 4; ++r) {
            const int row = ti * 16 + q * 4 + r;
            float mx = -1e30f;
#pragma unroll
            for (int tj = 0; tj < 4; ++tj) {
                const int col = tj * 16 + r16;
                float s = acc[ti][tj][r] * SCALE
                        + biasH[row * 64 + col] + maskW[row * 64 + col];
                acc[ti][tj][r] = s;
                mx = fmaxf(mx, s);
            }
#pragma unroll
            for (int d = 1; d < 16; d <<= 1)
                mx = fmaxf(mx, __shfl_xor(mx, d, 16));
            float sum = 0.f;
#pragma unroll
            for (int tj = 0; tj < 4; ++tj) {
                float e = exp2f((acc[ti][tj][r] - mx) * LOG2E);
                acc[ti][tj][r] = e;
                sum += e;
            }
#pragma unroll
            for (int d = 1; d < 16; d <<= 1)
                sum += __shfl_xor(sum, d, 16);
            const float inv = 1.0f / sum;
#pragma unroll
            for (int tj = 0; tj < 4; ++tj)
                Ps[row * 64 + tj * 16 + r16] = (bf16)(acc[ti][tj][r] * inv);
        }
    }
    __syncthreads();

    f32x4 o[4][2];
#pragma unroll
    for (int ti = 0; ti < 4; ++ti)
#pragma unroll
        for (int tn = 0; tn < 2; ++tn)
            o[ti][tn] = f32x4{0.f, 0.f, 0.f, 0.f};

#pragma unroll
    for (int ks = 0; ks < 2; ++ks) {
        bf16x8 av[4], bv[2];
#pragma unroll
        for (int ti = 0; ti < 4; ++ti)
            av[ti] = *(const bf16x8*)&Ps[(ti * 16 + r16) * 64 + ks * 32 + q * 8];
#pragma unroll
        for (int tn = 0; tn < 2; ++tn)
            bv[tn] = *(const bf16x8*)&Vt[(tn * 16 + r16) * 64 + ks * 32 + q * 8];
#pragma unroll
        for (int ti = 0; ti < 4; ++ti)
#pragma unroll
            for (int tn = 0; tn < 2; ++tn)
                o[ti][tn] = __builtin_amdgcn_mfma_f32_16x16x32_bf16(
                    av[ti], bv[tn], o[ti][tn], 0, 0, 0);
    }

    bf16* op = qbuf + rowbase * 512 + h * 32;
#pragma unroll
    for (int ti = 0; ti < 4; ++ti)
#pragma unroll
        for (int tn = 0; tn < 2; ++tn)
#pragma unroll
            for (int r = 0; r < 4; ++r)
                op[(long)(ti * 16 + q * 4 + r) * 512 + tn * 16 + r16] =
                    (bf16)(o[ti][tn][r]);
}

// ---------------------------------------------------------------------------
extern "C" void kernel_launch(void* const* d_in, const int* in_sizes, int n_in,
                              void* d_out, int out_size, void* d_ws, size_t ws_size,
                              hipStream_t stream) {
    const float* x      = (const float*)d_in[0];
    const float* mask   = (const float*)d_in[1];
    const float* qkv_w  = (const float*)d_in[2];
    const float* qkv_b  = (const float*)d_in[3];
    const float* table  = (const float*)d_in[4];
    const float* proj_w = (const float*)d_in[5];
    const float* proj_b = (const float*)d_in[6];
    const int*   relidx = (const int*)d_in[7];
    float* out = (float*)d_out;

    // ws layout (bytes):
    //   bias  @ 0          256 KB   fp32 (NH,64,64)
    //   qbuf  @ 262144     67.1 MB  bf16 q, then attn-out in place
    //   xbf   @ 67371008   67.1 MB  bf16 x
    //   wq    @ 134479872  1.57 MB  bf16 qkv_w
    //   wp    @ 136052736  0.52 MB  bf16 proj_w
    //   kv    @ 136577024  134.2 MB bf16 [k|v]  (or aliased to d_out if ws small)
    char*  ws   = (char*)d_ws;
    float* bias = (float*)ws;
    bf16*  qbuf = (bf16*)(ws + 262144);
    bf16*  xbf  = (bf16*)(ws + 67371008);
    bf16*  wq   = (bf16*)(ws + 134479872);
    bf16*  wp   = (bf16*)(ws + 136052736);
    const size_t need_full = 136577024ull + 134217728ull;  // 270.8 MB
    bf16* kvbuf = (ws_size >= need_full) ? (bf16*)(ws + 136577024)
                                         : (bf16*)d_out;

    bias_kernel<<<256, 256, 0, stream>>>(relidx, table, bias);
    cvt_kernel<<<2048, 256, 0, stream>>>(x,      xbf, 8388608);  // 33.5M elems
    cvt_kernel<<<768,  256, 0, stream>>>(qkv_w,  wq,  196608);
    cvt_kernel<<<256,  256, 0, stream>>>(proj_w, wp,  65536);

    gemm1_qkv8<<<1536, 512, 0, stream>>>(xbf, wq, qkv_b, qbuf, kvbuf);
    attn_kernel<<<16384, 64, 0, stream>>>(qbuf, kvbuf, mask, bias);
    gemm2_proj<<<dim3(512, 4), 256, 0, stream>>>(qbuf, wp, proj_b, out);
}

// Round 2
// 534.710 us; speedup vs baseline: 1.1551x; 1.0510x over previous
//
#include <hip/hip_runtime.h>
#include <hip/hip_bf16.h>

typedef __bf16 bf16;
typedef __bf16 bf16x4 __attribute__((ext_vector_type(4)));
typedef __bf16 bf16x8 __attribute__((ext_vector_type(8)));
typedef float  f32x4  __attribute__((ext_vector_type(4)));

#define AS1 __attribute__((address_space(1)))
#define AS3 __attribute__((address_space(3)))

__device__ __forceinline__ void gld_lds16(const void* g, void* l) {
    // async global->LDS, 16B per lane; LDS dest = wave-uniform base + lane*16
    __builtin_amdgcn_global_load_lds((AS1 void*)g, (AS3 void*)l, 16, 0, 0);
}

// ---------------------------------------------------------------------------
// fp32 -> bf16 bulk convert, float4-vectorized grid-stride
// ---------------------------------------------------------------------------
__global__ void cvt_kernel(const float* __restrict__ in, bf16* __restrict__ out,
                           int n4) {
    for (long i = (long)blockIdx.x * blockDim.x + threadIdx.x; i < n4;
         i += (long)gridDim.x * blockDim.x) {
        f32x4 v = ((const f32x4*)in)[i];
        bf16x4 h;
#pragma unroll
        for (int e = 0; e < 4; ++e) h[e] = (bf16)v[e];
        ((bf16x4*)out)[i] = h;
    }
}

// ---------------------------------------------------------------------------
// bias[h][i][j] = table[rel_index[i*64+j]][h]   (all fp32)
// ---------------------------------------------------------------------------
__global__ void bias_kernel(const int* __restrict__ rel_index,
                            const float* __restrict__ table,
                            float* __restrict__ bias) {
    int idx = blockIdx.x * 256 + threadIdx.x;   // 0..65535 = h*4096 + rc
    int rc = idx & 4095;
    int h  = idx >> 12;
    bias[idx] = table[rel_index[rc] * 16 + h];
}

// ---------------------------------------------------------------------------
// Shared 8-phase GEMM machinery (T3+T4+T5).  LDS tiles [slot][kk][256][32]
// bf16 (64-B rows).  Chunk-XOR swizzle: LDS (row, c16) holds global 16-B
// chunk (c16 ^ (row&3)); staged via pre-swizzled global source (rule #21),
// read with matching XOR -> 8 consecutive lanes hit 4 distinct chunk groups
// (2-way = free) instead of the 8-way (q-uniform chunk) pattern.
// ---------------------------------------------------------------------------
#define STAGE(GBASE, LBASE, SK0)                                          \
    { _Pragma("unroll")                                                   \
      for (int c_ = 0; c_ < 2; ++c_)                                      \
          gld_lds16((GBASE) + c_ * 16 * 512 + (SK0),                      \
                    (LBASE) + (w * 2 + c_) * 512); }

#define PHASE(S, KK, IH, LOADB, GB, LB, SK0, VM)                            \
  {                                                                         \
    const bf16* ap_ = sA + ((S)*2+(KK))*8192 + (wm128+(IH)*64+r16)*32 + cq8;\
    _Pragma("unroll")                                                       \
    for (int ii = 0; ii < 4; ++ii) av[ii] = *(const bf16x8*)(ap_ + ii*512); \
    if (LOADB) {                                                            \
      const bf16* bp_ = sB + ((S)*2+(KK))*8192 + (wn64+r16)*32 + cq8;       \
      _Pragma("unroll")                                                     \
      for (int jj = 0; jj < 4; ++jj) bv[jj] = *(const bf16x8*)(bp_+jj*512); \
    }                                                                       \
    STAGE(GB, LB, SK0);                                                     \
    __builtin_amdgcn_sched_barrier(0);                                      \
    __builtin_amdgcn_s_barrier();                                           \
    asm volatile("s_waitcnt lgkmcnt(0)");                                   \
    __builtin_amdgcn_sched_barrier(0);                                      \
    __builtin_amdgcn_s_setprio(1);                                          \
    _Pragma("unroll")                                                       \
    for (int ii = 0; ii < 4; ++ii)                                          \
      _Pragma("unroll")                                                     \
      for (int jj = 0; jj < 4; ++jj)                                        \
        acc[(IH)*4+ii][jj] = __builtin_amdgcn_mfma_f32_16x16x32_bf16(       \
            av[ii], bv[jj], acc[(IH)*4+ii][jj], 0, 0, 0);                   \
    __builtin_amdgcn_s_setprio(0);                                          \
    if (VM) asm volatile("s_waitcnt vmcnt(4)");                             \
    __builtin_amdgcn_sched_barrier(0);                                      \
    __builtin_amdgcn_s_barrier();                                           \
  }

#define GEMM_PREAMBLE                                                       \
    __shared__ __attribute__((aligned(16))) char smemraw[131072];           \
    bf16* sA = (bf16*)smemraw;                                              \
    bf16* sB = sA + 32768;                                                  \
    const int t     = threadIdx.x;                                          \
    const int w     = t >> 6;                                               \
    const int lane  = t & 63;                                               \
    const int q     = lane >> 4;                                            \
    const int r16   = lane & 15;                                            \
    const int wm128 = (w >> 2) * 128;                                       \
    const int wn64  = (w & 3) * 64;                                         \
    const int sc8   = (((lane & 3) ^ ((lane >> 2) & 3)) << 3);              \
    const int cq8   = ((q ^ (r16 & 3)) << 3);

#define GEMM_MAIN(ABASE, BBASE)                                             \
    const bf16* Ast = (ABASE) + (bM + w * 32 + (lane >> 2)) * 512 + sc8;    \
    const bf16* Bst = (BBASE) + (bN + w * 32 + (lane >> 2)) * 512 + sc8;    \
    f32x4 acc[8][4];                                                        \
    _Pragma("unroll")                                                       \
    for (int i = 0; i < 8; ++i)                                             \
        _Pragma("unroll")                                                   \
        for (int j = 0; j < 4; ++j) acc[i][j] = f32x4{0.f, 0.f, 0.f, 0.f};  \
    bf16x8 av[4], bv[4];                                                    \
    STAGE(Ast, sA + 0,     0);                                              \
    STAGE(Bst, sB + 0,     0);                                              \
    STAGE(Ast, sA + 8192,  32);                                             \
    STAGE(Bst, sB + 8192,  32);                                             \
    STAGE(Ast, sA + 16384, 64);                                             \
    STAGE(Bst, sB + 16384, 64);                                             \
    asm volatile("s_waitcnt vmcnt(4)");                                     \
    __builtin_amdgcn_sched_barrier(0);                                      \
    __builtin_amdgcn_s_barrier();                                           \
    for (int i = 0; i < 4; ++i) {                                           \
        const int t1 = 2 * i + 1;                                           \
        const int t2 = (2 * i + 2 < 8) ? 2 * i + 2 : 7;                     \
        const int t3 = (2 * i + 3 < 8) ? 2 * i + 3 : 7;                     \
        PHASE(0, 0, 0, 1, Ast, sA + 24576, t1 * 64 + 32, 0)                 \
        PHASE(0, 0, 1, 0, Bst, sB + 24576, t1 * 64 + 32, 0)                 \
        PHASE(0, 1, 1, 1, Ast, sA + 0,     t2 * 64,      0)                 \
        PHASE(0, 1, 0, 0, Bst, sB + 0,     t2 * 64,      1)                 \
        PHASE(1, 0, 0, 1, Ast, sA + 8192,  t2 * 64 + 32, 0)                 \
        PHASE(1, 0, 1, 0, Bst, sB + 8192,  t2 * 64 + 32, 0)                 \
        PHASE(1, 1, 1, 1, Ast, sA + 16384, t3 * 64,      0)                 \
        PHASE(1, 1, 0, 0, Bst, sB + 16384, t3 * 64,      1)                 \
    }                                                                       \
    asm volatile("s_waitcnt vmcnt(0)");                                     \
    __builtin_amdgcn_sched_barrier(0);                                      \
    __builtin_amdgcn_s_barrier();

// ---------------------------------------------------------------------------
// GEMM1 (qkv): M=65536, N=1536, K=512.  q part is pre-scaled by 1/sqrt(HD)
// (folded attention scale).  Epilogue via swizzled LDS C-tile -> 16B stores.
// ---------------------------------------------------------------------------
__global__ __launch_bounds__(512, 2) void gemm1_qkv8(
    const bf16* __restrict__ A, const bf16* __restrict__ B,
    const float* __restrict__ bias, bf16* __restrict__ Cq,
    bf16* __restrict__ Ckv)
{
    GEMM_PREAMBLE
    // XCD-chunked bijective swizzle (nwg=1536=8*192), N-fastest in chunk
    const int bid = blockIdx.x;
    const int wg  = (bid & 7) * 192 + (bid >> 3);
    const long bM = (long)(wg / 6) * 256;
    const long bN = (long)(wg % 6) * 256;

    GEMM_MAIN(A, B)

    const bool isQ = (bN < 512);                   // block-uniform
    const float sc = isQ ? 0.17677669529663687f : 1.0f;  // fold attn scale
    bf16* ct = (bf16*)smemraw;
#pragma unroll
    for (int j = 0; j < 4; ++j) {
        const int col  = wn64 + j * 16 + r16;
        const float bvv = bias[bN + col];
        const int chunk = col >> 3, cl = col & 7;
#pragma unroll
        for (int i = 0; i < 8; ++i)
#pragma unroll
            for (int r = 0; r < 4; ++r) {
                const int row = wm128 + i * 16 + q * 4 + r;
                ct[row * 256 + ((chunk ^ ((row >> 2) & 7)) << 3) + cl] =
                    (bf16)((acc[i][j][r] + bvv) * sc);
            }
    }
    __syncthreads();

    bf16* __restrict__ outp = isQ ? (Cq + bM * 512 + bN)
                                  : (Ckv + bM * 1024 + (bN - 512));
    const int ostr = isQ ? 512 : 1024;
#pragma unroll
    for (int it = 0; it < 16; ++it) {
        const int row = w * 32 + it * 2 + (lane >> 5);  // 2 full rows / wave
        const int c   = lane & 31;
        uint4 v = *(const uint4*)(ct + row * 256 +
                                  ((c ^ ((row >> 2) & 7)) << 3));
        *(uint4*)(outp + (long)row * ostr + c * 8) = v;
    }
}

// ---------------------------------------------------------------------------
// GEMM2 (proj): M=65536, N=512, K=512.  Same 8-phase template; direct fp32
// epilogue (C is the final output).
// ---------------------------------------------------------------------------
__global__ __launch_bounds__(512, 2) void gemm2_proj8(
    const bf16* __restrict__ A, const bf16* __restrict__ B,
    const float* __restrict__ bias, float* __restrict__ C)
{
    GEMM_PREAMBLE
    // nwg=512 = 8*64; 2 N-blocks per M-panel, N-fastest in chunk
    const int bid = blockIdx.x;
    const int wg  = (bid & 7) * 64 + (bid >> 3);
    const long bM = (long)(wg >> 1) * 256;
    const long bN = (long)(wg & 1) * 256;

    GEMM_MAIN(A, B)

#pragma unroll
    for (int j = 0; j < 4; ++j) {
        const long col = bN + wn64 + j * 16 + r16;
        const float bvv = bias[col];
#pragma unroll
        for (int i = 0; i < 8; ++i) {
            const long row = bM + wm128 + i * 16 + q * 4;
#pragma unroll
            for (int r = 0; r < 4; ++r)
                C[(row + r) * 512L + col] = acc[i][j][r] + bvv;
        }
    }
}

// ---------------------------------------------------------------------------
// Window attention: 4 heads (4 waves) per block; one window per block row.
// qbuf: (65536,512) bf16 = q (pre-scaled); kv: (65536,1024) bf16 = [k | v].
// Output staged in LDS then written coalesced into qbuf cols hg*128..+127.
// Per-head LDS region 12 KB: [Q 4K][K 4K][V 4K]; P (8K) over Q+K; o (4K)
// over Q after PV.  All tiles chunk-XOR swizzled (T2 analog) to kill the
// 8/16-way ds_read_b128 conflicts.
// ---------------------------------------------------------------------------
__global__ __launch_bounds__(256) void attn_kernel4(
    bf16* __restrict__ qbuf, const bf16* __restrict__ kv,
    const float* __restrict__ mask, const float* __restrict__ bias)
{
    __shared__ __attribute__((aligned(16))) bf16 smem[24576];  // 48 KB
    const int t    = threadIdx.x;
    const int wv   = t >> 6;                 // local head 0..3
    const int lane = t & 63;
    const int q    = lane >> 4;
    const int r16  = lane & 15;
    const int bw   = blockIdx.x >> 2;        // window 0..1023
    const int hg   = blockIdx.x & 3;         // head group
    const int h    = hg * 4 + wv;
    const int nw   = bw & 63;
    const long rowbase = (long)bw * 64;

    bf16* Qs = smem + wv * 6144;   // [64][32] chunk-swizzled (key=row&3)
    bf16* Ks = Qs + 2048;          // [64][32]
    bf16* Vt = Qs + 4096;          // [32][64] chunk-swizzled (key=row&7)
    bf16* Ps = Qs;                 // [64][64] chunk-swizzled (key=row&7)

    // stage Q,K (own head): pre-swizzled global chunk source
    const int sc8 = (((lane & 3) ^ ((lane >> 2) & 3)) << 3);
#pragma unroll
    for (int it = 0; it < 4; ++it) {
        const int tok = it * 16 + (lane >> 2);
        gld_lds16(qbuf + (rowbase + tok) * 512  + h * 32 + sc8, Qs + it * 512);
        gld_lds16(kv   + (rowbase + tok) * 1024 + h * 32 + sc8, Ks + it * 512);
    }
    // V row `lane` -> regs -> transposed+swizzled Vt
    {
        const bf16* gv = kv + (rowbase + lane) * 1024 + 512 + h * 32;
        uint4 vtmp[4];
#pragma unroll
        for (int jj = 0; jj < 4; ++jj) vtmp[jj] = ((const uint4*)gv)[jj];
        const bf16* vrow = (const bf16*)vtmp;
        const int tchunk = lane >> 3, tin = lane & 7;
#pragma unroll
        for (int hd = 0; hd < 32; ++hd)
            Vt[hd * 64 + ((tchunk ^ (hd & 7)) << 3) + tin] = vrow[hd];
    }
    asm volatile("s_waitcnt vmcnt(0)" ::: "memory");
    // no __syncthreads: each wave reads only its own head's region; DS ops
    // within a wave execute in order.

    const int cq8 = ((q ^ (r16 & 3)) << 3);
    f32x4 acc[4][4];
    {
        bf16x8 av[4], bv[4];
#pragma unroll
        for (int ti = 0; ti < 4; ++ti)
            av[ti] = *(const bf16x8*)&Qs[(ti * 16 + r16) * 32 + cq8];
#pragma unroll
        for (int tj = 0; tj < 4; ++tj)
            bv[tj] = *(const bf16x8*)&Ks[(tj * 16 + r16) * 32 + cq8];
        const f32x4 z = f32x4{0.f, 0.f, 0.f, 0.f};
#pragma unroll
        for (int ti = 0; ti < 4; ++ti)
#pragma unroll
            for (int tj = 0; tj < 4; ++tj)
                acc[ti][tj] = __builtin_amdgcn_mfma_f32_16x16x32_bf16(
                    av[ti], bv[tj], z, 0, 0, 0);
    }

    const float LOG2E  = 1.4426950408889634f;
    const float* biasH = bias + h * 4096;
    const float* maskW = mask + nw * 4096;

#pragma unroll
    for (int ti = 0; ti < 4; ++ti) {
#pragma unroll
        for (int r = 0; r < 4; ++r) {
            const int row = ti * 16 + q * 4 + r;
            float mx = -1e30f;
#pragma unroll
            for (int tj = 0; tj < 4; ++tj) {
                const int col = tj * 16 + r16;
                float s = acc[ti][tj][r]
                        + biasH[row * 64 + col] + maskW[row * 64 + col];
                acc[ti][tj][r] = s;
                mx = fmaxf(mx, s);
            }
#pragma unroll
            for (int d = 1; d < 16; d <<= 1)
                mx = fmaxf(mx, __shfl_xor(mx, d, 16));
            float sum = 0.f;
#pragma unroll
            for (int tj = 0; tj < 4; ++tj) {
                float e = exp2f((acc[ti][tj][r] - mx) * LOG2E);
                acc[ti][tj][r] = e;
                sum += e;
            }
#pragma unroll
            for (int d = 1; d < 16; d <<= 1)
                sum += __shfl_xor(sum, d, 16);
            const float inv = 1.0f / sum;
#pragma unroll
            for (int tj = 0; tj < 4; ++tj) {
                const int c = tj * 16 + r16;
                Ps[row * 64 + ((((c >> 3) ^ (row & 7)) << 3) + (c & 7))] =
                    (bf16)(acc[ti][tj][r] * inv);
            }
        }
    }

    f32x4 o[4][2];
#pragma unroll
    for (int ti = 0; ti < 4; ++ti)
#pragma unroll
        for (int tn = 0; tn < 2; ++tn)
            o[ti][tn] = f32x4{0.f, 0.f, 0.f, 0.f};

#pragma unroll
    for (int ks = 0; ks < 2; ++ks) {
        bf16x8 av[4], bv[2];
        const int ch = (((ks * 4 + q) ^ (r16 & 7)) << 3);
#pragma unroll
        for (int ti = 0; ti < 4; ++ti)
            av[ti] = *(const bf16x8*)&Ps[(ti * 16 + r16) * 64 + ch];
#pragma unroll
        for (int tn = 0; tn < 2; ++tn)
            bv[tn] = *(const bf16x8*)&Vt[(tn * 16 + r16) * 64 + ch];
#pragma unroll
        for (int ti = 0; ti < 4; ++ti)
#pragma unroll
            for (int tn = 0; tn < 2; ++tn)
                o[ti][tn] = __builtin_amdgcn_mfma_f32_16x16x32_bf16(
                    av[ti], bv[tn], o[ti][tn], 0, 0, 0);
    }

    // stage o into LDS (plain [64][32] at region base; P is dead now)
#pragma unroll
    for (int ti = 0; ti < 4; ++ti)
#pragma unroll
        for (int tn = 0; tn < 2; ++tn)
#pragma unroll
            for (int r = 0; r < 4; ++r)
                Qs[(ti * 16 + q * 4 + r) * 32 + tn * 16 + r16] =
                    (bf16)(o[ti][tn][r]);
    __syncthreads();

    // cooperative coalesced store: 64 rows x 128 cols (4 heads) bf16
    bf16* op = qbuf + rowbase * 512 + hg * 128;
#pragma unroll
    for (int it = 0; it < 4; ++it) {
        const int idx = it * 256 + t;            // 0..1023 16B-chunks
        const int row = idx >> 4;
        const int c   = idx & 15;
        const int hl  = c >> 2;
        uint4 v = *(const uint4*)(smem + hl * 6144 + row * 32 + (c & 3) * 8);
        *(uint4*)(op + (long)row * 512 + hl * 32 + (c & 3) * 8) = v;
    }
}

// ---------------------------------------------------------------------------
extern "C" void kernel_launch(void* const* d_in, const int* in_sizes, int n_in,
                              void* d_out, int out_size, void* d_ws, size_t ws_size,
                              hipStream_t stream) {
    const float* x      = (const float*)d_in[0];
    const float* mask   = (const float*)d_in[1];
    const float* qkv_w  = (const float*)d_in[2];
    const float* qkv_b  = (const float*)d_in[3];
    const float* table  = (const float*)d_in[4];
    const float* proj_w = (const float*)d_in[5];
    const float* proj_b = (const float*)d_in[6];
    const int*   relidx = (const int*)d_in[7];
    float* out = (float*)d_out;

    // ws layout (bytes):
    //   bias  @ 0          256 KB   fp32 (NH,64,64)
    //   qbuf  @ 262144     67.1 MB  bf16 q (pre-scaled), then attn-out in place
    //   xbf   @ 67371008   67.1 MB  bf16 x
    //   wq    @ 134479872  1.57 MB  bf16 qkv_w
    //   wp    @ 136052736  0.52 MB  bf16 proj_w
    //   kv    @ 136577024  134.2 MB bf16 [k|v]  (or aliased to d_out if ws small)
    char*  ws   = (char*)d_ws;
    float* bias = (float*)ws;
    bf16*  qbuf = (bf16*)(ws + 262144);
    bf16*  xbf  = (bf16*)(ws + 67371008);
    bf16*  wq   = (bf16*)(ws + 134479872);
    bf16*  wp   = (bf16*)(ws + 136052736);
    const size_t need_full = 136577024ull + 134217728ull;  // 270.8 MB
    bf16* kvbuf = (ws_size >= need_full) ? (bf16*)(ws + 136577024)
                                         : (bf16*)d_out;

    bias_kernel<<<256, 256, 0, stream>>>(relidx, table, bias);
    cvt_kernel<<<2048, 256, 0, stream>>>(x,      xbf, 8388608);  // 33.5M elems
    cvt_kernel<<<768,  256, 0, stream>>>(qkv_w,  wq,  196608);
    cvt_kernel<<<256,  256, 0, stream>>>(proj_w, wp,  65536);

    gemm1_qkv8<<<1536, 512, 0, stream>>>(xbf, wq, qkv_b, qbuf, kvbuf);
    attn_kernel4<<<4096, 256, 0, stream>>>(qbuf, kvbuf, mask, bias);
    gemm2_proj8<<<512, 512, 0, stream>>>(qbuf, wp, proj_b, out);
}